// Round 1
// baseline (51.115 us; speedup 1.0000x reference)
//
#include <hip/hip_runtime.h>

#define NDIM   16
#define MCOLS  2048
#define NANG   120           // 16*15/2
#define BLOCK  256
#define COLS_PER_WG 1024     // 256 threads * 4 cols (float4)

__global__ __launch_bounds__(BLOCK) void soot_kernel(
    const float* __restrict__ X,
    const float* __restrict__ angles,
    const float* __restrict__ mus,
    float* __restrict__ out)
{
    __shared__ float c_lds[NANG];
    __shared__ float s_lds[NANG];
    __shared__ __align__(16) float R_lds[NDIM * NDIM];

    const int wg   = blockIdx.x;
    const int b    = wg >> 1;      // block index
    const int half = wg & 1;       // which half of the 2048 columns
    const int tid  = threadIdx.x;

    // Stage 1: 120 threads compute cos/sin of the angles into LDS.
    if (tid < NANG) {
        float a = angles[b * NANG + tid];
        float sv, cv;
        sincosf(a, &sv, &cv);
        c_lds[tid] = cv;
        s_lds[tid] = sv;
    }
    __syncthreads();

    // Stage 2: 16 threads (thread j owns column j of M) run the Givens cascade.
    // Each rotation mixes rows iTop/iBtm; columns are independent.
    if (tid < NDIM) {
        const int j = tid;
        float m[NDIM];
#pragma unroll
        for (int r = 0; r < NDIM; ++r) m[r] = (r == j) ? 1.0f : 0.0f;
        int k = 0;
#pragma unroll
        for (int iTop = 0; iTop < NDIM - 1; ++iTop) {
            float vt = m[iTop];
#pragma unroll
            for (int iBtm = iTop + 1; iBtm < NDIM; ++iBtm) {
                const float c  = c_lds[k];
                const float s  = s_lds[k];
                const float vb = m[iBtm];
                const float nvt = c * vt - s * vb;
                m[iBtm] = s * vt + c * vb;
                vt = nvt;
                ++k;
            }
            m[iTop] = vt;
        }
        // Row-scale by mus and write R (row-major) to LDS.
#pragma unroll
        for (int r = 0; r < NDIM; ++r)
            R_lds[r * NDIM + j] = mus[b * NDIM + r] * m[r];
    }
    __syncthreads();

    // Stage 3: out[b, :, col..col+3] = R @ X[b, :, col..col+3], float4 per thread.
    const int col = half * COLS_PER_WG + tid * 4;
    const float* Xb = X   + (size_t)b * NDIM * MCOLS;
    float*       Ob = out + (size_t)b * NDIM * MCOLS;

    float4 x4[NDIM];
#pragma unroll
    for (int jj = 0; jj < NDIM; ++jj)
        x4[jj] = *reinterpret_cast<const float4*>(Xb + jj * MCOLS + col);

#pragma unroll
    for (int r = 0; r < NDIM; ++r) {
        float4 acc = make_float4(0.f, 0.f, 0.f, 0.f);
#pragma unroll
        for (int q = 0; q < 4; ++q) {
            const float4 w = *reinterpret_cast<const float4*>(&R_lds[r * NDIM + q * 4]);
#pragma unroll
            for (int t = 0; t < 4; ++t) {
                const float wv = (&w.x)[t];
                const float4 xv = x4[q * 4 + t];
                acc.x = fmaf(wv, xv.x, acc.x);
                acc.y = fmaf(wv, xv.y, acc.y);
                acc.z = fmaf(wv, xv.z, acc.z);
                acc.w = fmaf(wv, xv.w, acc.w);
            }
        }
        *reinterpret_cast<float4*>(Ob + r * MCOLS + col) = acc;
    }
}

extern "C" void kernel_launch(void* const* d_in, const int* in_sizes, int n_in,
                              void* d_out, int out_size, void* d_ws, size_t ws_size,
                              hipStream_t stream) {
    const float* X      = (const float*)d_in[0];
    const float* angles = (const float*)d_in[1];
    const float* mus    = (const float*)d_in[2];
    float* out          = (float*)d_out;

    const int nblks = in_sizes[1] / NANG;          // 1024
    dim3 grid(nblks * (MCOLS / COLS_PER_WG));      // 2 workgroups per block
    dim3 block(BLOCK);
    hipLaunchKernelGGL(soot_kernel, grid, block, 0, stream,
                       X, angles, mus, out);
}

// Round 3
// 47.831 us; speedup vs baseline: 1.0686x; 1.0686x over previous
//
#include <hip/hip_runtime.h>

#define NDIM   16
#define MCOLS  2048
#define NANG   120           // 16*15/2
#define BLOCK  256
#define COLS_PER_WG 1024     // 256 threads * 4 cols (float4)

typedef float f32x4 __attribute__((ext_vector_type(4)));

__global__ __launch_bounds__(BLOCK) void soot_kernel(
    const float* __restrict__ X,
    const float* __restrict__ angles,
    const float* __restrict__ mus,
    float* __restrict__ out)
{
    __shared__ float c_lds[NANG];
    __shared__ float s_lds[NANG];
    __shared__ __align__(16) float R_lds[NDIM * NDIM];

    const int wg   = blockIdx.x;
    const int b    = wg >> 1;      // block index
    const int half = wg & 1;       // which half of the 2048 columns
    const int tid  = threadIdx.x;

    // Stage 1: wave 0 computes cos/sin of the 120 angles into LDS (2 per lane).
    if (tid < 64) {
#pragma unroll
        for (int rep = 0; rep < 2; ++rep) {
            const int k = tid + rep * 64;
            if (k < NANG) {
                float a = angles[b * NANG + k];
                float sv, cv;
                sincosf(a, &sv, &cv);
                c_lds[k] = cv;
                s_lds[k] = sv;
            }
        }
    }
    __syncthreads();

    // Stage 2: 16 threads (thread j owns column j of M) run the Givens cascade.
    if (tid < NDIM) {
        const int j = tid;
        float m[NDIM];
#pragma unroll
        for (int r = 0; r < NDIM; ++r) m[r] = (r == j) ? 1.0f : 0.0f;
        int k = 0;
#pragma unroll
        for (int iTop = 0; iTop < NDIM - 1; ++iTop) {
            float vt = m[iTop];
#pragma unroll
            for (int iBtm = iTop + 1; iBtm < NDIM; ++iBtm) {
                const float c  = c_lds[k];
                const float s  = s_lds[k];
                const float vb = m[iBtm];
                const float nvt = c * vt - s * vb;
                m[iBtm] = s * vt + c * vb;
                vt = nvt;
                ++k;
            }
            m[iTop] = vt;
        }
        // Row-scale by mus and write R (row-major) to LDS.
#pragma unroll
        for (int r = 0; r < NDIM; ++r)
            R_lds[r * NDIM + j] = mus[b * NDIM + r] * m[r];
    }
    __syncthreads();

    // Stage 3: out[b, :, col..col+3] = R @ X[b, :, col..col+3], f32x4 per thread.
    const int col = half * COLS_PER_WG + tid * 4;
    const float* Xb = X   + (size_t)b * NDIM * MCOLS;
    float*       Ob = out + (size_t)b * NDIM * MCOLS;

    f32x4 x4[NDIM];
#pragma unroll
    for (int jj = 0; jj < NDIM; ++jj)
        x4[jj] = *reinterpret_cast<const f32x4*>(Xb + jj * MCOLS + col);

#pragma unroll
    for (int r = 0; r < NDIM; ++r) {
        f32x4 acc = (f32x4)(0.f);
#pragma unroll
        for (int q = 0; q < 4; ++q) {
            const f32x4 w = *reinterpret_cast<const f32x4*>(&R_lds[r * NDIM + q * 4]);
#pragma unroll
            for (int t = 0; t < 4; ++t) {
                const float wv = w[t];
                acc += wv * x4[q * 4 + t];
            }
        }
        // Nontemporal: out is write-once, never re-read — don't let it evict X
        // from L2/L3 (X can then stay Infinity-Cache-resident across replays).
        __builtin_nontemporal_store(acc, reinterpret_cast<f32x4*>(Ob + r * MCOLS + col));
    }
}

extern "C" void kernel_launch(void* const* d_in, const int* in_sizes, int n_in,
                              void* d_out, int out_size, void* d_ws, size_t ws_size,
                              hipStream_t stream) {
    const float* X      = (const float*)d_in[0];
    const float* angles = (const float*)d_in[1];
    const float* mus    = (const float*)d_in[2];
    float* out          = (float*)d_out;

    const int nblks = in_sizes[1] / NANG;          // 1024
    dim3 grid(nblks * (MCOLS / COLS_PER_WG));      // 2 workgroups per block
    dim3 block(BLOCK);
    hipLaunchKernelGGL(soot_kernel, grid, block, 0, stream,
                       X, angles, mus, out);
}